// Round 11
// baseline (222.367 us; speedup 1.0000x reference)
//
#include <hip/hip_runtime.h>
#include <stdint.h>

// out[b] = argmax_k cos(h_b, A_k), int32, first-index ties.
// prep: rn[k]; a8s = frag-ordered int8(A*rn*QS); h8 = row-major int8(h_n*QS).
// score: h-tile resident in LDS (staged once, verified swizzle), BARRIER-FREE
//        K-loop: A-frags prefetched global->VGPR (ping-pong, 1 chunk ahead),
//        i8 MFMA 16x16x64, rank by raw int dot; per-row top-3/block -> cand.
// refine: exact fp32 rescore of top-8 of 48 candidates per row.

#define DIM 512
#define B_ROWS 4096
#define K_ROWS 32768
#define BT 128
#define KT 128
#define NKT (K_ROWS / KT)    // 256
#define KSLOTS 16            // grid = 32*16 = 512 = 2 blocks/CU (LDS-bound)
#define NKTPB (NKT / KSLOTS) // 16 k-tiles per block
#define NCHUNK 4             // 128-byte D chunks
#define QSCALE (127.0f / 0.26f)

typedef __attribute__((ext_vector_type(4))) float fx4;
typedef __attribute__((ext_vector_type(4))) int int4v;
typedef unsigned long long u64;

__device__ __forceinline__ uint32_t ford(float s) {
    uint32_t u = __float_as_uint(s);
    return u ^ ((uint32_t)((int32_t)u >> 31) | 0x80000000u);
}
__device__ __forceinline__ u64 umax64(u64 a, u64 b) { return a > b ? a : b; }
__device__ __forceinline__ u64 umin64(u64 a, u64 b) { return a < b ? a : b; }
__device__ __forceinline__ uint32_t umax32(uint32_t a, uint32_t b) { return a > b ? a : b; }
__device__ __forceinline__ uint32_t umin32(uint32_t a, uint32_t b) { return a < b ? a : b; }

__device__ __forceinline__ int q8(float x, float qs) {
    int v = __float2int_rn(x * qs);
    return v < -127 ? -127 : (v > 127 ? 127 : v);
}

// Fused prep, one wave per row.
// A rows -> frag-ordered a8s: byte A[kt*128 + wn*64 + ni*16 + m][dc*128 + ks*64 + q*16 + j]
//   stored at kt*65536 + dc*16384 + wn*8192 + ni*2048 + ks*1024 + (q*16+m)*16 + j
//   (score reads lane-contiguous 16B frags: lane = q*16+m).
// h rows -> row-major h8.
__global__ __launch_bounds__(256) void prep_kernel(const float* __restrict__ A,
                                                   const float* __restrict__ h,
                                                   char* __restrict__ a8s,
                                                   char* __restrict__ h8,
                                                   float* __restrict__ rn) {
    const int lane = threadIdx.x & 63, wid = threadIdx.x >> 6;
    const bool isA = blockIdx.x < 8192;
    const int row = (isA ? blockIdx.x : blockIdx.x - 8192) * 4 + wid;
    const float* src = (isA ? A : h) + (size_t)row * DIM;

    const fx4* p = (const fx4*)src;
    fx4 a = p[lane * 2], b = p[lane * 2 + 1];
    float ss = a[0]*a[0] + a[1]*a[1] + a[2]*a[2] + a[3]*a[3]
             + b[0]*b[0] + b[1]*b[1] + b[2]*b[2] + b[3]*b[3];
    #pragma unroll
    for (int off = 32; off > 0; off >>= 1) ss += __shfl_xor(ss, off, 64);
    float r = 1.0f / fmaxf(sqrtf(ss), 1e-8f);
    if (isA && lane == 0) rn[row] = r;

    float qs = r * QSCALE;
    int v0 = q8(a[0], qs), v1 = q8(a[1], qs), v2 = q8(a[2], qs), v3 = q8(a[3], qs);
    int v4 = q8(b[0], qs), v5 = q8(b[1], qs), v6 = q8(b[2], qs), v7 = q8(b[3], qs);
    uint32_t lo = (uint32_t)(v0 & 255) | ((uint32_t)(v1 & 255) << 8)
                | ((uint32_t)(v2 & 255) << 16) | ((uint32_t)(v3 & 255) << 24);
    uint32_t hi = (uint32_t)(v4 & 255) | ((uint32_t)(v5 & 255) << 8)
                | ((uint32_t)(v6 & 255) << 16) | ((uint32_t)(v7 & 255) << 24);

    if (!isA) {
        *reinterpret_cast<uint2*>(h8 + (size_t)row * DIM + lane * 8) = make_uint2(lo, hi);
    } else {
        // source bytes d = lane*8 .. +7 of this row
        int kt = row >> 7, wnr = (row >> 6) & 1, ni = (row >> 4) & 3, m = row & 15;
        int dc = lane >> 4, rem = lane & 15;
        int ks = rem >> 3, q = (rem >> 1) & 3, j0 = (lane & 1) * 8;
        size_t off = (size_t)kt * 65536 + (size_t)dc * 16384 + wnr * 8192
                   + ni * 2048 + ks * 1024 + q * 256 + m * 16 + j0;
        *reinterpret_cast<uint2*>(a8s + off) = make_uint2(lo, hi);
    }
}

typedef __attribute__((address_space(3))) uint32_t lds_u32;
typedef __attribute__((address_space(1))) const uint32_t g_u32;

// 64 KB resident h tile; barrier-free K-loop; A via register prefetch.
__global__ __launch_bounds__(256, 2) void score_kernel(
    const char* __restrict__ h8, const char* __restrict__ a8s,
    u64* __restrict__ cand)
{
    __shared__ __attribute__((aligned(16))) char smem[65536];

    const int t = threadIdx.x, lane = t & 63, wid = t >> 6;
    const int wm = wid >> 1, wn = wid & 1;
    const int lr = lane & 15, q = lane >> 4;
    const int btile = blockIdx.x & 31, kslot = blockIdx.x >> 5;  // 32 peers share A
    const int b0 = btile * BT;

    const int srow = lane >> 3;
    const int scol = (lane & 7) ^ srow;
    const int s7 = lr & 7;
    const int sw0 = (q ^ s7) * 16;        // kstep 0: granule q (swizzled)
    const int sw1 = ((4 + q) ^ s7) * 16;  // kstep 1: granule 4+q

    // ---- stage whole h tile once: hf[dc][row 128][granule 8], swizzled ----
    {
        const char* hsrc = h8 + (size_t)b0 * DIM;
        #pragma unroll
        for (int i = 0; i < 16; i++) {
            int issue = wid * 16 + i;          // dc = issue>>4 = wid, rb = i
            int dc = issue >> 4, rb = issue & 15;
            const char* g = hsrc + (size_t)(rb * 8 + srow) * DIM + dc * 128 + scol * 16;
            __builtin_amdgcn_global_load_lds((g_u32*)g, (lds_u32*)(smem + issue * 1024), 16, 0, 0);
        }
    }
    __syncthreads();

    uint32_t v1[16], v2[16];
    #pragma unroll
    for (int s = 0; s < 16; s++) { v1[s] = 0u; v2[s] = 0u; }

    const char* abase = a8s + (size_t)lane * 16 + wn * 8192;
    #define A_ADDR(cc) (abase + (size_t)(kslot + ((cc) >> 2) * KSLOTS) * 65536 \
                              + (size_t)((cc) & 3) * 16384)

    int4v Ab[2][8];
    {   // prefetch chunk 0
        const char* nb = A_ADDR(0);
        #pragma unroll
        for (int u = 0; u < 8; u++)
            Ab[0][u] = *reinterpret_cast<const int4v*>(nb + (u >> 1) * 2048 + (u & 1) * 1024);
    }

    #pragma unroll 1
    for (int kt_i = 0; kt_i < NKTPB; kt_i++) {
        int4v acc[4][4];
        #pragma unroll
        for (int mi = 0; mi < 4; mi++)
            #pragma unroll
            for (int ni = 0; ni < 4; ni++)
                acc[mi][ni] = (int4v){0, 0, 0, 0};

        #pragma unroll
        for (int dc = 0; dc < NCHUNK; dc++) {
            const int cc = kt_i * 4 + dc;
            const int ncc = (cc < NKTPB * 4 - 1) ? cc + 1 : cc;
            // issue next chunk's A loads (land while this chunk's MFMAs run)
            const char* nb = A_ADDR(ncc);
            #pragma unroll
            for (int u = 0; u < 8; u++)
                Ab[(dc + 1) & 1][u] =
                    *reinterpret_cast<const int4v*>(nb + (u >> 1) * 2048 + (u & 1) * 1024);

            const char* hc = smem + dc * 16384;
            #pragma unroll
            for (int mi = 0; mi < 4; mi++) {
                const char* hb = hc + (wm * 64 + mi * 16 + lr) * 128;
                int4v h0 = *reinterpret_cast<const int4v*>(hb + sw0);
                int4v h1 = *reinterpret_cast<const int4v*>(hb + sw1);
                #pragma unroll
                for (int ni = 0; ni < 4; ni++) {
                    acc[mi][ni] = __builtin_amdgcn_mfma_i32_16x16x64_i8(
                        h0, Ab[dc & 1][ni * 2], acc[mi][ni], 0, 0, 0);
                    acc[mi][ni] = __builtin_amdgcn_mfma_i32_16x16x64_i8(
                        h1, Ab[dc & 1][ni * 2 + 1], acc[mi][ni], 0, 0, 0);
                }
            }
        }

        const uint32_t metabase = (uint32_t)(kt_i << 2);
        #pragma unroll
        for (int mi = 0; mi < 4; mi++)
            #pragma unroll
            for (int ni = 0; ni < 4; ni++) {
                const uint32_t meta = metabase | (uint32_t)ni;
                #pragma unroll
                for (int r = 0; r < 4; r++) {
                    uint32_t ord = (uint32_t)acc[mi][ni][r] ^ 0x80000000u;
                    uint32_t pk = (ord & 0xFFFFFFC0u) | meta;
                    int s = mi * 4 + r;
                    uint32_t lo = umin32(v1[s], pk);
                    v1[s] = umax32(v1[s], pk);
                    v2[s] = umax32(v2[s], lo);
                }
            }
    }

    // block top-3 per row via u32 LDS (stride 33, reuses h LDS)
    uint32_t* cl = (uint32_t*)smem;
    u64 g1 = 0, g2 = 0, g3 = 0;
    for (int pass = 0; pass < 2; pass++) {
        __syncthreads();
        #pragma unroll
        for (int s = 0; s < 16; s++) {
            int mi = s >> 2, r = s & 3;
            int row_local = wm * 64 + mi * 16 + q * 4 + r;
            cl[row_local * 33 + wn * 16 + lr] = pass ? v2[s] : v1[s];
        }
        __syncthreads();
        if (t < BT) {
            #pragma unroll 4
            for (int j = 0; j < 32; j++) {
                uint32_t pv = cl[t * 33 + j];
                uint32_t meta = pv & 63u;
                int k = (kslot + (int)(meta >> 2) * KSLOTS) * KT
                      + (j >> 4) * 64 + (int)(meta & 3u) * 16 + (j & 15);
                u64 e = ((u64)(pv & 0xFFFFFFC0u) << 32) | (u64)(~(uint32_t)k);
                u64 t1 = umax64(g1, e), t2 = umin64(g1, e);
                g3 = umax64(g3, umin64(g2, t2));
                g2 = umax64(g2, t2);
                g1 = t1;
            }
        }
    }
    if (t < BT) {
        size_t base = ((size_t)(b0 + t) * KSLOTS + kslot) * 3;
        cand[base] = g1;
        cand[base + 1] = g2;
        cand[base + 2] = g3;
    }
}

// one wave per row: top-8 of 48 candidates, exact fp32 rescore, argmax.
__global__ __launch_bounds__(256) void refine_kernel(
    const float* __restrict__ h, const float* __restrict__ A,
    const float* __restrict__ rn, const u64* __restrict__ cand,
    int* __restrict__ out)
{
    const int t = threadIdx.x, lane = t & 63, wid = t >> 6;
    const int row = blockIdx.x * 4 + wid;
    const u64* cr = cand + (size_t)row * (KSLOTS * 3);
    u64 x = (lane < KSLOTS * 3) ? cr[lane] : 0ULL;

    u64 sel[8];
    #pragma unroll
    for (int j = 0; j < 8; j++) {
        u64 v = x;
        #pragma unroll
        for (int m = 32; m >= 1; m >>= 1) v = umax64(v, __shfl_xor(v, m, 64));
        sel[j] = v;
        if (x == v) x = 0;
    }

    const fx4* hp = reinterpret_cast<const fx4*>(h + (size_t)row * DIM);
    fx4 h0 = hp[lane * 2], h1 = hp[lane * 2 + 1];

    u64 best = 0;
    #pragma unroll
    for (int j = 0; j < 8; j++) {
        uint32_t kg = ~(uint32_t)sel[j];
        const fx4* ap = reinterpret_cast<const fx4*>(A + (size_t)kg * DIM);
        fx4 a0 = ap[lane * 2], a1 = ap[lane * 2 + 1];
        float s = h0[0]*a0[0] + h0[1]*a0[1] + h0[2]*a0[2] + h0[3]*a0[3]
                + h1[0]*a1[0] + h1[1]*a1[1] + h1[2]*a1[2] + h1[3]*a1[3];
        #pragma unroll
        for (int m = 32; m >= 1; m >>= 1) s += __shfl_xor(s, m, 64);
        s *= rn[kg];
        u64 pk = ((u64)ford(s) << 32) | (u64)(~kg);
        best = umax64(best, pk);
    }
    if (lane == 0) out[row] = (int)(~(uint32_t)best);
}

extern "C" void kernel_launch(void* const* d_in, const int* in_sizes, int n_in,
                              void* d_out, int out_size, void* d_ws, size_t ws_size,
                              hipStream_t stream) {
    const float* h = (const float*)d_in[0];   // [4096, 512]
    const float* A = (const float*)d_in[1];   // [32768, 512]
    int* out = (int*)d_out;                   // [4096] int32

    // ws: a8s (16MB) | h8 (2MB) | rn (128KB) | cand (1.5MB)
    char* w = (char*)d_ws;
    char* a8s = w;
    char* h8 = w + (size_t)K_ROWS * DIM;
    float* rn = (float*)(w + (size_t)(K_ROWS + B_ROWS) * DIM);
    u64* cand = (u64*)(w + (size_t)(K_ROWS + B_ROWS) * DIM
                         + (size_t)K_ROWS * sizeof(float));

    prep_kernel<<<8192 + 1024, 256, 0, stream>>>(A, h, a8s, h8, rn);
    score_kernel<<<32 * KSLOTS, 256, 0, stream>>>(h8, a8s, cand);
    refine_kernel<<<B_ROWS / 4, 256, 0, stream>>>(h, A, rn, cand, out);
}